// Round 5
// baseline (156.256 us; speedup 1.0000x reference)
//
#include <hip/hip_runtime.h>
#include <hip/hip_bf16.h>

typedef __attribute__((ext_vector_type(8))) short bf16x8;
typedef __attribute__((ext_vector_type(4))) float f32x4;
typedef __attribute__((ext_vector_type(16))) float f32x16;

#define NHID 256
#define NDIM 128
#define NB   512

__device__ __forceinline__ unsigned pk2bf(float a, float b) {
  float2 f; f.x = a; f.y = b;
  __hip_bfloat162 h = __float22bfloat162_rn(f);
  unsigned r;
  __builtin_memcpy(&r, &h, 4);
  return r;
}

// ---------------- setup ----------------
// hx = x@Wx^T + b0, hy = y@Wy^T  (8 rows per block: W0 row loaded once, reused 8x)
// W1/W2 -> bf16 fragment-major for 32x32x16 MFMA:
//   frag f = kt*8 + gtile  (kt = k>>4, gtile = g>>5), 1 KB each.
//   lane l = (g&31) + 32*((k>>3)&1) holds W[g][kt*16 + (l>>5)*8 .. +8] as 8 bf16 at l*16 bytes.
__global__ void k_setup(const float* __restrict__ x, const float* __restrict__ y,
                        const float* __restrict__ W0, const float* __restrict__ b0,
                        const float* __restrict__ W1, const float* __restrict__ W2,
                        float* __restrict__ hx, float* __restrict__ hy,
                        unsigned short* __restrict__ W1f, unsigned short* __restrict__ W2f) {
  int bid = blockIdx.x, tid = threadIdx.x;
  if (bid < 128) {
    int which = bid & 1;                 // 0: hx (+b0), 1: hy
    int rowbase = (bid >> 1) * 8;
    const float* in = which ? y : x;
    const f32x4* wr = (const f32x4*)(W0 + tid * (2 * NDIM) + which * NDIM);
    f32x4 sv[8];
#pragma unroll
    for (int r = 0; r < 8; ++r) sv[r] = f32x4{0.f, 0.f, 0.f, 0.f};
#pragma unroll 4
    for (int i = 0; i < NDIM / 4; ++i) {
      f32x4 b = wr[i];
#pragma unroll
      for (int r = 0; r < 8; ++r) {
        f32x4 a = *(const f32x4*)(in + (rowbase + r) * NDIM + i * 4);
        sv[r] += a * b;
      }
    }
    float bb = which ? 0.f : b0[tid];
    float* o = (which ? hy : hx) + rowbase * NHID + tid;
#pragma unroll
    for (int r = 0; r < 8; ++r)
      o[r * NHID] = sv[r][0] + sv[r][1] + sv[r][2] + sv[r][3] + bb;
  } else {
    int i = ((bid - 128) * 256 + tid) * 4;        // 2*65536 elements total
    const float* src = W1; unsigned short* dst = W1f; int j = i;
    if (i >= NHID * NHID) { src = W2; dst = W2f; j = i - NHID * NHID; }
    float4 v = *(const float4*)(src + j);
    int g = j >> 8, k0 = j & 255;                 // 4 consecutive k, same g
    int f = ((k0 >> 4) << 3) + (g >> 5);
    int l = (g & 31) + (((k0 >> 3) & 1) << 5);
    uint2 pk; pk.x = pk2bf(v.x, v.y); pk.y = pk2bf(v.z, v.w);
    *(uint2*)(dst + f * 512 + l * 8 + (k0 & 7)) = pk;
  }
}

// ---------------- per-task body ----------------
// Layer tiles: wave wv covers g in [wv*32,+32), m in [0,128), 32x32x16 MFMA.
// LDS h fragment-major: frag(kt, mt) at (kt*4 + mt)*1024 bytes, lane's 16B at lane*16 holds
//   h[m = mt*32 + (lane&31)][k = kt*16 + (lane>>5)*8 .. +8].
// M1 consumes cur with register-resident W1 (w1r) and, when BUILD, interleaves the
// h0-build of the NEXT task into nxt (one build iter per odd kt; global loads issued
// 4 kt ahead via 2 ping-pong register slots).
template <bool BUILD>
__device__ __forceinline__ void run_task(
    char* __restrict__ cur, char* __restrict__ nxt,
    const bf16x8 (&w1r)[16],
    const unsigned short* __restrict__ fb2,   // W2f + wv*512 + lane*8
    const float* __restrict__ pxr2,           // hx row ptr (+l5*8 + kbase*16)
    const float* __restrict__ pyr2,           // hy next-task row ptr (same offsets)
    char* __restrict__ wb,                    // nxt + (kbase*4+mt_b)*1024 + lane*16
    const float* __restrict__ bias1, const float* __restrict__ bias2,
    const float* __restrict__ w3, const float* __restrict__ b3,
    float* __restrict__ out, int a0i, int bb0,
    int wv, int lane, int c, int l5, int tid) {
  const f32x4 vzero = {0.f, 0.f, 0.f, 0.f};
  const char* sl = cur + lane * 16;

  f32x16 acc[4];
#pragma unroll
  for (int j = 0; j < 4; ++j)
#pragma unroll
    for (int e = 0; e < 16; ++e) acc[j][e] = 0.f;

  // build prefetch slots (depth 2)
  f32x4 bx0[2], bx1[2], by0[2], by1[2];
  if (BUILD) {
#pragma unroll
    for (int s = 0; s < 2; ++s) {
      bx0[s] = *(const f32x4*)(pxr2 + s * 16);
      bx1[s] = *(const f32x4*)(pxr2 + s * 16 + 4);
      by0[s] = *(const f32x4*)(pyr2 + s * 16);
      by1[s] = *(const f32x4*)(pyr2 + s * 16 + 4);
    }
  }

  // ---- M1: layer 1 from cur (W1 in registers) + interleaved build into nxt ----
#pragma unroll
  for (int kt = 0; kt < 16; ++kt) {
    bf16x8 B0 = *(const bf16x8*)(sl + kt * 4096);
    bf16x8 B1 = *(const bf16x8*)(sl + kt * 4096 + 1024);
    bf16x8 B2 = *(const bf16x8*)(sl + kt * 4096 + 2048);
    bf16x8 B3 = *(const bf16x8*)(sl + kt * 4096 + 3072);
    __builtin_amdgcn_s_setprio(1);
    acc[0] = __builtin_amdgcn_mfma_f32_32x32x16_bf16(w1r[kt], B0, acc[0], 0, 0, 0);
    acc[1] = __builtin_amdgcn_mfma_f32_32x32x16_bf16(w1r[kt], B1, acc[1], 0, 0, 0);
    acc[2] = __builtin_amdgcn_mfma_f32_32x32x16_bf16(w1r[kt], B2, acc[2], 0, 0, 0);
    acc[3] = __builtin_amdgcn_mfma_f32_32x32x16_bf16(w1r[kt], B3, acc[3], 0, 0, 0);
    __builtin_amdgcn_s_setprio(0);
    if (BUILD && (kt & 1)) {
      int j = kt >> 1;                      // 0..7
      int s = j & 1;
      f32x4 a = __builtin_elementwise_max(bx0[s] + by0[s], vzero);
      f32x4 b = __builtin_elementwise_max(bx1[s] + by1[s], vzero);
      uint4 pk;
      pk.x = pk2bf(a[0], a[1]);
      pk.y = pk2bf(a[2], a[3]);
      pk.z = pk2bf(b[0], b[1]);
      pk.w = pk2bf(b[2], b[3]);
      *(uint4*)(wb + j * 4096) = pk;
      if (j + 2 < 8) {
        bx0[s] = *(const f32x4*)(pxr2 + (j + 2) * 16);
        bx1[s] = *(const f32x4*)(pxr2 + (j + 2) * 16 + 4);
        by0[s] = *(const f32x4*)(pyr2 + (j + 2) * 16);
        by1[s] = *(const f32x4*)(pyr2 + (j + 2) * 16 + 4);
      }
    }
  }
  __syncthreads();

  // W2 prefetch (latency hides under the epilogue VALU)
  bf16x8 a0 = *(const bf16x8*)(fb2);
  bf16x8 a1 = *(const bf16x8*)(fb2 + 4096);

  // ---- layer-1 epilogue: h1 = relu(acc + b1) back into cur, fragment-major ----
  // acc[mt][r]: m = mt*32 + c, g = wv*32 + rg*8 + l5*4 + (r&3)  (rg = r>>2).
  {
#pragma unroll
    for (int rg = 0; rg < 4; ++rg) {
      f32x4 bv = *(const f32x4*)(bias1 + wv * 32 + rg * 8 + l5 * 4);
      char* wa = cur + (c + ((rg & 1) << 5)) * 16 + l5 * 8;
      int fbase = (wv * 2 + (rg >> 1)) * 4;
#pragma unroll
      for (int mt = 0; mt < 4; ++mt) {
        f32x16 v = acc[mt];
        f32x4 t = {v[rg * 4 + 0], v[rg * 4 + 1], v[rg * 4 + 2], v[rg * 4 + 3]};
        t = __builtin_elementwise_max(t + bv, vzero);
        uint2 pk;
        pk.x = pk2bf(t[0], t[1]);
        pk.y = pk2bf(t[2], t[3]);
        *(uint2*)(wa + (fbase + mt) * 1024) = pk;
      }
    }
  }
  __syncthreads();

  // ---- M2: layer 2 from cur (W2 prefetch rotation, distance 2) ----
#pragma unroll
  for (int j = 0; j < 4; ++j)
#pragma unroll
    for (int e = 0; e < 16; ++e) acc[j][e] = 0.f;

#pragma unroll
  for (int kt = 0; kt < 16; kt += 2) {
    {
      bf16x8 B0 = *(const bf16x8*)(sl + kt * 4096);
      bf16x8 B1 = *(const bf16x8*)(sl + kt * 4096 + 1024);
      bf16x8 B2 = *(const bf16x8*)(sl + kt * 4096 + 2048);
      bf16x8 B3 = *(const bf16x8*)(sl + kt * 4096 + 3072);
      __builtin_amdgcn_s_setprio(1);
      acc[0] = __builtin_amdgcn_mfma_f32_32x32x16_bf16(a0, B0, acc[0], 0, 0, 0);
      acc[1] = __builtin_amdgcn_mfma_f32_32x32x16_bf16(a0, B1, acc[1], 0, 0, 0);
      acc[2] = __builtin_amdgcn_mfma_f32_32x32x16_bf16(a0, B2, acc[2], 0, 0, 0);
      acc[3] = __builtin_amdgcn_mfma_f32_32x32x16_bf16(a0, B3, acc[3], 0, 0, 0);
      __builtin_amdgcn_s_setprio(0);
      if (kt + 2 < 16) a0 = *(const bf16x8*)(fb2 + (kt + 2) * 4096);
    }
    {
      bf16x8 B0 = *(const bf16x8*)(sl + (kt + 1) * 4096);
      bf16x8 B1 = *(const bf16x8*)(sl + (kt + 1) * 4096 + 1024);
      bf16x8 B2 = *(const bf16x8*)(sl + (kt + 1) * 4096 + 2048);
      bf16x8 B3 = *(const bf16x8*)(sl + (kt + 1) * 4096 + 3072);
      __builtin_amdgcn_s_setprio(1);
      acc[0] = __builtin_amdgcn_mfma_f32_32x32x16_bf16(a1, B0, acc[0], 0, 0, 0);
      acc[1] = __builtin_amdgcn_mfma_f32_32x32x16_bf16(a1, B1, acc[1], 0, 0, 0);
      acc[2] = __builtin_amdgcn_mfma_f32_32x32x16_bf16(a1, B2, acc[2], 0, 0, 0);
      acc[3] = __builtin_amdgcn_mfma_f32_32x32x16_bf16(a1, B3, acc[3], 0, 0, 0);
      __builtin_amdgcn_s_setprio(0);
      if (kt + 3 < 16) a1 = *(const bf16x8*)(fb2 + (kt + 3) * 4096);
    }
  }

  // ---- head: out = relu(acc + b2) . w3, reduced over g ----
  float s[4];
  {
    f32x4 sv[4];
#pragma unroll
    for (int mt = 0; mt < 4; ++mt) sv[mt] = vzero;
#pragma unroll
    for (int rg = 0; rg < 4; ++rg) {
      int g0 = wv * 32 + rg * 8 + l5 * 4;
      f32x4 bv  = *(const f32x4*)(bias2 + g0);
      f32x4 wvv = *(const f32x4*)(w3 + g0);
#pragma unroll
      for (int mt = 0; mt < 4; ++mt) {
        f32x16 v = acc[mt];
        f32x4 t = {v[rg * 4 + 0], v[rg * 4 + 1], v[rg * 4 + 2], v[rg * 4 + 3]};
        t = __builtin_elementwise_max(t + bv, vzero);
        sv[mt] += t * wvv;
      }
    }
#pragma unroll
    for (int mt = 0; mt < 4; ++mt) {
      float t = sv[mt][0] + sv[mt][1] + sv[mt][2] + sv[mt][3];
      t += __shfl_xor(t, 32);            // combine the two l5 halves
      s[mt] = t;
    }
  }

  __syncthreads();                    // all LDS reads of layer-2 done; reuse cur as staging
  float* stg = (float*)cur;           // [8 waves][128 m]
  if (l5 == 0) {
#pragma unroll
    for (int mt = 0; mt < 4; ++mt) stg[wv * 128 + mt * 32 + c] = s[mt];
  }
  __syncthreads();

  if (tid < 128) {
    float v = b3[0];
#pragma unroll
    for (int w = 0; w < 8; ++w) v += stg[w * 128 + tid];
    out[(a0i + (tid >> 4)) * NB + bb0 + (tid & 15)] = v;
  }
  __syncthreads();   // protect stg reads from next task's build writes into cur
}

// ---------------- main fused kernel: persistent-ish, 4 tasks (128 pairs each) per block ----------------
__global__ __launch_bounds__(512, 2) void k_main(
    const float* __restrict__ hx, const float* __restrict__ hy,
    const unsigned short* __restrict__ W1f, const unsigned short* __restrict__ W2f,
    const float* __restrict__ bias1, const float* __restrict__ bias2,
    const float* __restrict__ w3, const float* __restrict__ b3,
    float* __restrict__ out) {
  extern __shared__ __align__(16) char dbuf[];   // 2 x 64 KB h-buffers
  char* bufA = dbuf;
  char* bufB = dbuf + 65536;

  const int tid = threadIdx.x;
  const int bid = blockIdx.x;
  const int task0 = bid * 4;                 // 4 consecutive tasks share the a-group
  const int a0i = (task0 >> 5) * 8;          // a-rows [a0i, a0i+8)
  int bb0 = (task0 & 31) * 16;               // b-cols advance by 16 per task

  const int lane = tid & 63, wv = tid >> 6;  // 8 waves
  const int c = lane & 31, l5 = lane >> 5;
  const int mt_b = wv & 3, kbase = (wv >> 2) * 8;
  const int m = mt_b * 32 + c;
  const f32x4 vzero = {0.f, 0.f, 0.f, 0.f};

  // per-thread constant pointers for the build phase
  const float* pxr2 = hx + (a0i + (m >> 4)) * NHID + l5 * 8 + kbase * 16;
  const float* hyr  = hy + (m & 15) * NHID + l5 * 8 + kbase * 16;  // + bb0*NHID per task
  const int wboff = (kbase * 4 + mt_b) * 1024 + lane * 16;

  // W1 wave-fragments -> registers (reused across all 4 tasks)
  bf16x8 w1r[16];
  const unsigned short* fb1 = W1f + wv * 512 + lane * 8;
#pragma unroll
  for (int kt = 0; kt < 16; ++kt) w1r[kt] = *(const bf16x8*)(fb1 + kt * 4096);

  const unsigned short* fb2 = W2f + wv * 512 + lane * 8;

  // ---- prologue: build task0's h0 into bufA (plain) ----
  {
    const float* py = hyr + bb0 * NHID;
    char* wbp = bufA + wboff;
#pragma unroll
    for (int j = 0; j < 8; ++j) {
      f32x4 x0 = *(const f32x4*)(pxr2 + j * 16);
      f32x4 x1 = *(const f32x4*)(pxr2 + j * 16 + 4);
      f32x4 y0 = *(const f32x4*)(py + j * 16);
      f32x4 y1 = *(const f32x4*)(py + j * 16 + 4);
      f32x4 a = __builtin_elementwise_max(x0 + y0, vzero);
      f32x4 b = __builtin_elementwise_max(x1 + y1, vzero);
      uint4 pk;
      pk.x = pk2bf(a[0], a[1]);
      pk.y = pk2bf(a[2], a[3]);
      pk.z = pk2bf(b[0], b[1]);
      pk.w = pk2bf(b[2], b[3]);
      *(uint4*)(wbp + j * 4096) = pk;
    }
  }
  __syncthreads();

  // ---- tasks 0..2: compute + build-next interleaved ----
  char* cur = bufA;
  char* nxt = bufB;
  for (int t = 0; t < 3; ++t) {
    run_task<true>(cur, nxt, w1r, fb2, pxr2, hyr + (bb0 + 16) * NHID, nxt + wboff,
                   bias1, bias2, w3, b3, out, a0i, bb0, wv, lane, c, l5, tid);
    char* tmp = cur; cur = nxt; nxt = tmp;
    bb0 += 16;
  }
  // ---- task 3: compute only ----
  run_task<false>(cur, nxt, w1r, fb2, pxr2, hyr, nxt + wboff,
                  bias1, bias2, w3, b3, out, a0i, bb0, wv, lane, c, l5, tid);
}

extern "C" void kernel_launch(void* const* d_in, const int* in_sizes, int n_in,
                              void* d_out, int out_size, void* d_ws, size_t ws_size,
                              hipStream_t stream) {
  const float* x  = (const float*)d_in[0];
  const float* y  = (const float*)d_in[1];
  const float* W0 = (const float*)d_in[2];
  const float* b0 = (const float*)d_in[3];
  const float* W1 = (const float*)d_in[4];
  const float* b1 = (const float*)d_in[5];
  const float* W2 = (const float*)d_in[6];
  const float* b2 = (const float*)d_in[7];
  const float* W3 = (const float*)d_in[8];
  const float* b3 = (const float*)d_in[9];
  float* out = (float*)d_out;

  char* ws = (char*)d_ws;
  float* hx = (float*)ws;                               // 512*256*4 = 512 KB
  float* hy = (float*)(ws + 524288);                    // 512 KB
  unsigned short* W1f = (unsigned short*)(ws + 1048576);          // 128 KB
  unsigned short* W2f = (unsigned short*)(ws + 1048576 + 131072); // 128 KB

  static bool attr_set = false;
  if (!attr_set) {
    hipFuncSetAttribute(reinterpret_cast<const void*>(k_main),
                        hipFuncAttributeMaxDynamicSharedMemorySize, 131072);
    attr_set = true;
  }

  k_setup<<<dim3(256), dim3(256), 0, stream>>>(x, y, W0, b0, W1, W2, hx, hy, W1f, W2f);
  k_main<<<dim3(512), dim3(512), 131072, stream>>>(hx, hy, W1f, W2f, b1, b2, W3, b3, out);
}

// Round 6
// 91.340 us; speedup vs baseline: 1.7107x; 1.7107x over previous
//
#include <hip/hip_runtime.h>
#include <hip/hip_bf16.h>

typedef __attribute__((ext_vector_type(8))) short bf16x8;
typedef __attribute__((ext_vector_type(4))) float f32x4;
typedef __attribute__((ext_vector_type(16))) float f32x16;

#define NHID 256
#define NDIM 128
#define NB   512

__device__ __forceinline__ unsigned pk2bf(float a, float b) {
  float2 f; f.x = a; f.y = b;
  __hip_bfloat162 h = __float22bfloat162_rn(f);
  unsigned r;
  __builtin_memcpy(&r, &h, 4);
  return r;
}

// ---------------- setup ----------------
// hx = x@Wx^T + b0, hy = y@Wy^T  (8 rows per block: W0 row loaded once, reused 8x)
// W1/W2 -> bf16 fragment-major for 32x32x16 MFMA:
//   frag f = kt*8 + gtile  (kt = k>>4, gtile = g>>5), 1 KB each.
//   lane l = (g&31) + 32*((k>>3)&1) holds W[g][kt*16 + (l>>5)*8 .. +8] as 8 bf16 at l*16 bytes.
__global__ void k_setup(const float* __restrict__ x, const float* __restrict__ y,
                        const float* __restrict__ W0, const float* __restrict__ b0,
                        const float* __restrict__ W1, const float* __restrict__ W2,
                        float* __restrict__ hx, float* __restrict__ hy,
                        unsigned short* __restrict__ W1f, unsigned short* __restrict__ W2f) {
  int bid = blockIdx.x, tid = threadIdx.x;
  if (bid < 128) {
    int which = bid & 1;                 // 0: hx (+b0), 1: hy
    int rowbase = (bid >> 1) * 8;
    const float* in = which ? y : x;
    const f32x4* wr = (const f32x4*)(W0 + tid * (2 * NDIM) + which * NDIM);
    f32x4 sv[8];
#pragma unroll
    for (int r = 0; r < 8; ++r) sv[r] = f32x4{0.f, 0.f, 0.f, 0.f};
#pragma unroll 4
    for (int i = 0; i < NDIM / 4; ++i) {
      f32x4 b = wr[i];
#pragma unroll
      for (int r = 0; r < 8; ++r) {
        f32x4 a = *(const f32x4*)(in + (rowbase + r) * NDIM + i * 4);
        sv[r] += a * b;
      }
    }
    float bb = which ? 0.f : b0[tid];
    float* o = (which ? hy : hx) + rowbase * NHID + tid;
#pragma unroll
    for (int r = 0; r < 8; ++r)
      o[r * NHID] = sv[r][0] + sv[r][1] + sv[r][2] + sv[r][3] + bb;
  } else {
    int i = ((bid - 128) * 256 + tid) * 4;        // 2*65536 elements total
    const float* src = W1; unsigned short* dst = W1f; int j = i;
    if (i >= NHID * NHID) { src = W2; dst = W2f; j = i - NHID * NHID; }
    float4 v = *(const float4*)(src + j);
    int g = j >> 8, k0 = j & 255;                 // 4 consecutive k, same g
    int f = ((k0 >> 4) << 3) + (g >> 5);
    int l = (g & 31) + (((k0 >> 3) & 1) << 5);
    uint2 pk; pk.x = pk2bf(v.x, v.y); pk.y = pk2bf(v.z, v.w);
    *(uint2*)(dst + f * 512 + l * 8 + (k0 & 7)) = pk;
  }
}

// ---------------- layer loop: wave tile 64g x 128m, 32x32x16 MFMA, 4 waves ----------------
// LDS h fragment-major: frag(kt, mt) at (kt*4 + mt)*1024 bytes, lane's 16B at lane*16 holds
//   h[m = mt*32 + (lane&31)][k = kt*16 + (lane>>5)*8 .. +8].
// Wave wv: g in [wv*64, +64)  (gtiles 2wv, 2wv+1), m in [0,128).
// SOFTWARE PIPELINE: B-fragments (LDS) ping-pong double-buffered — the ds_reads for
// kt+1 are issued BEFORE the MFMA octet of kt, so lgkmcnt waits hide under MFMA.
// A-fragments (global) rotate with prefetch distance 2 as before.
// PRE2: final iteration issues the first four A-fragments of the NEXT layer.
template <bool PRE2>
__device__ __forceinline__ void layer_loop(const unsigned short* __restrict__ fb,
                                           const char* __restrict__ src_lane, // buf + lane*16
                                           f32x16 acc[2][4],
                                           bf16x8 a00, bf16x8 a01, bf16x8 a10, bf16x8 a11,
                                           const unsigned short* __restrict__ fb2,
                                           bf16x8& p00, bf16x8& p01, bf16x8& p10, bf16x8& p11) {
#pragma unroll
  for (int i = 0; i < 2; ++i)
#pragma unroll
    for (int j = 0; j < 4; ++j)
#pragma unroll
      for (int e = 0; e < 16; ++e) acc[i][j][e] = 0.f;

  // prime the B pipeline with kt=0
  bf16x8 Bc0 = *(const bf16x8*)(src_lane);
  bf16x8 Bc1 = *(const bf16x8*)(src_lane + 1024);
  bf16x8 Bc2 = *(const bf16x8*)(src_lane + 2048);
  bf16x8 Bc3 = *(const bf16x8*)(src_lane + 3072);

#pragma unroll
  for (int kt = 0; kt < 16; kt += 2) {
    {
      // issue kt+1 B-reads first; their wait lands under the MFMA octet below
      bf16x8 Bn0 = *(const bf16x8*)(src_lane + (kt + 1) * 4096);
      bf16x8 Bn1 = *(const bf16x8*)(src_lane + (kt + 1) * 4096 + 1024);
      bf16x8 Bn2 = *(const bf16x8*)(src_lane + (kt + 1) * 4096 + 2048);
      bf16x8 Bn3 = *(const bf16x8*)(src_lane + (kt + 1) * 4096 + 3072);
      __builtin_amdgcn_s_setprio(1);
      acc[0][0] = __builtin_amdgcn_mfma_f32_32x32x16_bf16(a00, Bc0, acc[0][0], 0, 0, 0);
      acc[1][0] = __builtin_amdgcn_mfma_f32_32x32x16_bf16(a01, Bc0, acc[1][0], 0, 0, 0);
      acc[0][1] = __builtin_amdgcn_mfma_f32_32x32x16_bf16(a00, Bc1, acc[0][1], 0, 0, 0);
      acc[1][1] = __builtin_amdgcn_mfma_f32_32x32x16_bf16(a01, Bc1, acc[1][1], 0, 0, 0);
      acc[0][2] = __builtin_amdgcn_mfma_f32_32x32x16_bf16(a00, Bc2, acc[0][2], 0, 0, 0);
      acc[1][2] = __builtin_amdgcn_mfma_f32_32x32x16_bf16(a01, Bc2, acc[1][2], 0, 0, 0);
      acc[0][3] = __builtin_amdgcn_mfma_f32_32x32x16_bf16(a00, Bc3, acc[0][3], 0, 0, 0);
      acc[1][3] = __builtin_amdgcn_mfma_f32_32x32x16_bf16(a01, Bc3, acc[1][3], 0, 0, 0);
      __builtin_amdgcn_s_setprio(0);
      if (kt + 2 < 16) {
        a00 = *(const bf16x8*)(fb + (kt + 2) * 4096);
        a01 = *(const bf16x8*)(fb + (kt + 2) * 4096 + 512);
      }
      Bc0 = Bn0; Bc1 = Bn1; Bc2 = Bn2; Bc3 = Bn3;
    }
    {
      // issue kt+2 B-reads (if any) before the kt+1 MFMA octet
      bf16x8 Bn0, Bn1, Bn2, Bn3;
      if (kt + 2 < 16) {
        Bn0 = *(const bf16x8*)(src_lane + (kt + 2) * 4096);
        Bn1 = *(const bf16x8*)(src_lane + (kt + 2) * 4096 + 1024);
        Bn2 = *(const bf16x8*)(src_lane + (kt + 2) * 4096 + 2048);
        Bn3 = *(const bf16x8*)(src_lane + (kt + 2) * 4096 + 3072);
      }
      __builtin_amdgcn_s_setprio(1);
      acc[0][0] = __builtin_amdgcn_mfma_f32_32x32x16_bf16(a10, Bc0, acc[0][0], 0, 0, 0);
      acc[1][0] = __builtin_amdgcn_mfma_f32_32x32x16_bf16(a11, Bc0, acc[1][0], 0, 0, 0);
      acc[0][1] = __builtin_amdgcn_mfma_f32_32x32x16_bf16(a10, Bc1, acc[0][1], 0, 0, 0);
      acc[1][1] = __builtin_amdgcn_mfma_f32_32x32x16_bf16(a11, Bc1, acc[1][1], 0, 0, 0);
      acc[0][2] = __builtin_amdgcn_mfma_f32_32x32x16_bf16(a10, Bc2, acc[0][2], 0, 0, 0);
      acc[1][2] = __builtin_amdgcn_mfma_f32_32x32x16_bf16(a11, Bc2, acc[1][2], 0, 0, 0);
      acc[0][3] = __builtin_amdgcn_mfma_f32_32x32x16_bf16(a10, Bc3, acc[0][3], 0, 0, 0);
      acc[1][3] = __builtin_amdgcn_mfma_f32_32x32x16_bf16(a11, Bc3, acc[1][3], 0, 0, 0);
      __builtin_amdgcn_s_setprio(0);
      if (kt + 3 < 16) {
        a10 = *(const bf16x8*)(fb + (kt + 3) * 4096);
        a11 = *(const bf16x8*)(fb + (kt + 3) * 4096 + 512);
      } else if (PRE2) {
        p00 = *(const bf16x8*)(fb2);
        p01 = *(const bf16x8*)(fb2 + 512);
        p10 = *(const bf16x8*)(fb2 + 4096);
        p11 = *(const bf16x8*)(fb2 + 4096 + 512);
      }
      if (kt + 2 < 16) { Bc0 = Bn0; Bc1 = Bn1; Bc2 = Bn2; Bc3 = Bn3; }
    }
  }
}

// ---------------- main fused kernel: 128 pairs (8 a x 16 b) per block, 256 threads ----------------
__global__ __launch_bounds__(256, 2) void k_main(
    const float* __restrict__ hx, const float* __restrict__ hy,
    const unsigned short* __restrict__ W1f, const unsigned short* __restrict__ W2f,
    const float* __restrict__ bias1, const float* __restrict__ bias2,
    const float* __restrict__ w3, const float* __restrict__ b3,
    float* __restrict__ out) {
  __shared__ __align__(16) char buf[65536];   // h0 -> h1 (in place), then out-staging

  const int tid = threadIdx.x;
  const int bid = blockIdx.x;
  const int a0i = (bid >> 5) * 8;    // 64 a-tile groups of 8
  const int bb0 = (bid & 31) * 16;   // 32 b-tile groups

  const int lane = tid & 63, wv = tid >> 6;   // 4 waves
  const int c = lane & 31, l5 = lane >> 5;
  const f32x4 vzero = {0.f, 0.f, 0.f, 0.f};

  const unsigned short* fb1 = W1f + wv * 1024 + lane * 8;   // + kt*4096, +512 for 2nd gtile
  const unsigned short* fb2 = W2f + wv * 1024 + lane * 8;

  // issue layer-1 A prefetch immediately; latency hides under the h0 build
  bf16x8 a00 = *(const bf16x8*)(fb1);
  bf16x8 a01 = *(const bf16x8*)(fb1 + 512);
  bf16x8 a10 = *(const bf16x8*)(fb1 + 4096);
  bf16x8 a11 = *(const bf16x8*)(fb1 + 4096 + 512);

  // ---- build h0: thread (wv, lane) fills 16B of frag(kt, mt = wv) for all 16 kt ----
  // h0[m][k] = relu(hx'[a0i + m>>4][k] + hy[bb0 + (m&15)][k]),  m = wv*32 + c
  {
    const float* pxr = hx + (a0i + wv * 2 + (c >> 4)) * NHID + l5 * 8;
    const float* pyr = hy + (bb0 + (c & 15)) * NHID + l5 * 8;
    char* wbase = buf + wv * 1024 + lane * 16;
#pragma unroll
    for (int j = 0; j < 16; ++j) {
      int ko = j * 16;
      f32x4 x0 = *(const f32x4*)(pxr + ko);
      f32x4 x1 = *(const f32x4*)(pxr + ko + 4);
      f32x4 y0 = *(const f32x4*)(pyr + ko);
      f32x4 y1 = *(const f32x4*)(pyr + ko + 4);
      f32x4 a = __builtin_elementwise_max(x0 + y0, vzero);
      f32x4 b = __builtin_elementwise_max(x1 + y1, vzero);
      uint4 pk;
      pk.x = pk2bf(a[0], a[1]);
      pk.y = pk2bf(a[2], a[3]);
      pk.z = pk2bf(b[0], b[1]);
      pk.w = pk2bf(b[2], b[3]);
      *(uint4*)(wbase + j * 4096) = pk;
    }
  }
  __syncthreads();

  const char* src_lane = buf + lane * 16;
  f32x16 acc[2][4];
  bf16x8 w2a00, w2a01, w2a10, w2a11;

  // ---- layer 1 (also prefetches layer-2 A frags in its tail) ----
  layer_loop<true>(fb1, src_lane, acc, a00, a01, a10, a11, fb2, w2a00, w2a01, w2a10, w2a11);
  __syncthreads();

  // ---- layer-1 epilogue: h1[m][g] = relu(acc + b1) back into fragment-major LDS ----
  // acc[gt][mt][r]: m = mt*32 + c, g = wv*64 + gt*32 + rg*8 + l5*4 + (r&3)  (rg = r>>2).
  // Dest frag f' = (g>>4)*4 + (m>>5) = ((wv*4 + gt*2 + (rg>>1)))*4 + mt,
  //   lane slot l' = c + 32*(rg&1), byte l'*16 + l5*8 (8B store of 4 bf16).
  {
#pragma unroll
    for (int gt = 0; gt < 2; ++gt) {
#pragma unroll
      for (int rg = 0; rg < 4; ++rg) {
        f32x4 bv = *(const f32x4*)(bias1 + wv * 64 + gt * 32 + rg * 8 + l5 * 4);
        char* wa = buf + (c + ((rg & 1) << 5)) * 16 + l5 * 8;
        int fbase = (wv * 4 + gt * 2 + (rg >> 1)) * 4;
#pragma unroll
        for (int mt = 0; mt < 4; ++mt) {
          f32x16 v = acc[gt][mt];
          f32x4 t = {v[rg * 4 + 0], v[rg * 4 + 1], v[rg * 4 + 2], v[rg * 4 + 3]};
          t = __builtin_elementwise_max(t + bv, vzero);
          uint2 pk;
          pk.x = pk2bf(t[0], t[1]);
          pk.y = pk2bf(t[2], t[3]);
          *(uint2*)(wa + (fbase + mt) * 1024) = pk;
        }
      }
    }
  }
  __syncthreads();

  // ---- layer 2 + head folded into registers ----
  {
    bf16x8 d0, d1, d2, d3;   // dummies (no further prefetch)
    layer_loop<false>(fb2, src_lane, acc, w2a00, w2a01, w2a10, w2a11, fb2, d0, d1, d2, d3);
  }

  float s[4];
  {
    f32x4 sv[4];
#pragma unroll
    for (int mt = 0; mt < 4; ++mt) sv[mt] = vzero;
#pragma unroll
    for (int gt = 0; gt < 2; ++gt) {
#pragma unroll
      for (int rg = 0; rg < 4; ++rg) {
        int g0 = wv * 64 + gt * 32 + rg * 8 + l5 * 4;
        f32x4 bv  = *(const f32x4*)(bias2 + g0);
        f32x4 wvv = *(const f32x4*)(w3 + g0);
#pragma unroll
        for (int mt = 0; mt < 4; ++mt) {
          f32x16 v = acc[gt][mt];
          f32x4 t = {v[rg * 4 + 0], v[rg * 4 + 1], v[rg * 4 + 2], v[rg * 4 + 3]};
          t = __builtin_elementwise_max(t + bv, vzero);
          sv[mt] += t * wvv;
        }
      }
    }
#pragma unroll
    for (int mt = 0; mt < 4; ++mt) {
      float t = sv[mt][0] + sv[mt][1] + sv[mt][2] + sv[mt][3];
      t += __shfl_xor(t, 32);            // combine the two l5 halves (different g-quads)
      s[mt] = t;
    }
  }

  __syncthreads();                    // all LDS reads of layer-2 done; reuse buf as staging
  float* stg = (float*)buf;           // [4 waves][128 m]
  if (l5 == 0) {
#pragma unroll
    for (int mt = 0; mt < 4; ++mt) stg[wv * 128 + mt * 32 + c] = s[mt];
  }
  __syncthreads();

  if (tid < 128) {
    float v = b3[0];
#pragma unroll
    for (int w = 0; w < 4; ++w) v += stg[w * 128 + tid];
    out[(a0i + (tid >> 4)) * NB + bb0 + (tid & 15)] = v;
  }
}

extern "C" void kernel_launch(void* const* d_in, const int* in_sizes, int n_in,
                              void* d_out, int out_size, void* d_ws, size_t ws_size,
                              hipStream_t stream) {
  const float* x  = (const float*)d_in[0];
  const float* y  = (const float*)d_in[1];
  const float* W0 = (const float*)d_in[2];
  const float* b0 = (const float*)d_in[3];
  const float* W1 = (const float*)d_in[4];
  const float* b1 = (const float*)d_in[5];
  const float* W2 = (const float*)d_in[6];
  const float* b2 = (const float*)d_in[7];
  const float* W3 = (const float*)d_in[8];
  const float* b3 = (const float*)d_in[9];
  float* out = (float*)d_out;

  char* ws = (char*)d_ws;
  float* hx = (float*)ws;                               // 512*256*4 = 512 KB
  float* hy = (float*)(ws + 524288);                    // 512 KB
  unsigned short* W1f = (unsigned short*)(ws + 1048576);          // 128 KB
  unsigned short* W2f = (unsigned short*)(ws + 1048576 + 131072); // 128 KB

  k_setup<<<dim3(256), dim3(256), 0, stream>>>(x, y, W0, b0, W1, W2, hx, hy, W1f, W2f);
  k_main<<<dim3(2048), dim3(256), 0, stream>>>(hx, hy, W1f, W2f, b1, b2, W3, b3, out);
}